// Round 19
// baseline (23.261 us; speedup 1.0000x reference)
//
#include <hip/hip_runtime.h>
#include <math.h>

// Problem constants
#define BINS   256
#define NPAIR  24        // B*C = 8*3
#define NPIX   16384     // 128*128
#define SPLIT  32        // blocks per (tensor,channel) — R19 delta (6 blk/CU)
#define NBLK   (48 * SPLIT)   // 1536 blocks

#define DELTA    0.003921568859f           // 1/255 (bin pitch)
// exp2-folded constants
#define NK2      -7213.475204f             // -5000 * log2(e)
#define A2K2     56.57627611f              // (10000/255) * log2(e)
#define B2K2     0.11093398f               // 5000*DELTA^2 * log2(e)
#define RHO1     0.85745468f               // rho   = exp(-2*5000*DELTA^2)
#define RHO3     0.63042510f               // rho^3
#define RHO4     0.54056079f               // rho^4
#define INV_NORM 39.894228040143274f       // 1/(sigma*sqrt(2*pi))

typedef float v2f __attribute__((ext_vector_type(2)));

// ---------------------------------------------------------------------------
// Kernel 1: soft histogram, register-gather, 16 bins/lane, paired recurrence,
// 2 pixels/round (R16 body). R19 delta: SPLIT 16->32 (3->6 blocks/CU).
// Rationale: R11's occupancy-null was on the READLANE variant (no memory ops
// in loop — issue-bound). This variant's loop starts with 2 dependent
// ds_read_b32 (~120cyc); 3 waves/SIMD can't hide that -> test 6 blocks/CU.
// VGPR ~36 (R14 evidence), LDS 18KB -> 6 resident fits easily.
// ---------------------------------------------------------------------------
__global__ __launch_bounds__(256) void hist_kernel(
    const float* __restrict__ targ, const float* __restrict__ pred,
    float* __restrict__ g_part) {
  __shared__ float h[4][4][BINS];   // [wave][subgroup][bin] = 16 KiB
  __shared__ float pxs[512];        // block's pixel slab (512 px)

  const int t = threadIdx.x, lane = t & 63, wv = t >> 6;
  const int g = lane >> 4, lsub = lane & 15;
  const int pg = blockIdx.x >> 5;            // 0..47
  const int split = blockIdx.x & (SPLIT - 1);
  const int chan = (pg < NPAIR) ? pg : pg - NPAIR;
  const float* __restrict__ src = (pg < NPAIR) ? targ : pred;

  // stage 512 pixels: 256 threads x float2 (coalesced)
  reinterpret_cast<float2*>(pxs)[t] =
      reinterpret_cast<const float2*>(src + chan * NPIX + split * 512)[t];
  __syncthreads();

  const float c0 = (float)(16 * lsub) * DELTA;  // lane's first bin center
  const v2f RHO13 = {RHO1, RHO3};
  const v2f RHO44 = {RHO4, RHO4};

  v2f acc[8];
  #pragma unroll
  for (int i = 0; i < 8; ++i) acc[i] = (v2f){0.f, 0.f};

  #pragma unroll 2
  for (int r = 0; r < 16; ++r) {
    // subgroup g's two pixels this round (uniform per 16-lane subgroup)
    const float xA = pxs[wv * 128 + 8 * r + g];
    const float xB = pxs[wv * 128 + 8 * r + 4 + g];

    const float dA = xA - c0;
    const float dB = xB - c0;
    const float w0A = __builtin_amdgcn_exp2f(NK2 * dA * dA);
    const float w0B = __builtin_amdgcn_exp2f(NK2 * dB * dB);
    const float q0A = __builtin_amdgcn_exp2f(A2K2 * dA - B2K2);
    const float q0B = __builtin_amdgcn_exp2f(A2K2 * dB - B2K2);

    v2f wA; wA.x = w0A; wA.y = w0A * q0A;
    v2f wB; wB.x = w0B; wB.y = w0B * q0B;
    v2f mA = (q0A * q0A) * RHO13;
    v2f mB = (q0B * q0B) * RHO13;
    acc[0] += wA + wB;
    #pragma unroll
    for (int i = 1; i < 8; ++i) {
      wA *= mA; wB *= mB;      // two independent chains
      mA *= RHO44; mB *= RHO44;
      acc[i] += wA + wB;
    }
  }

  // block combine: 16 (wave,subgroup) partials -> one 256-bin block partial
  #pragma unroll
  for (int i = 0; i < 8; i += 2)
    reinterpret_cast<float4*>(&h[wv][g][16 * lsub + 2 * i])[0] =
        make_float4(acc[i].x, acc[i].y, acc[i + 1].x, acc[i + 1].y);
  __syncthreads();

  float s = 0.f;
  #pragma unroll
  for (int w2 = 0; w2 < 4; ++w2)
    #pragma unroll
    for (int g2 = 0; g2 < 4; ++g2) s += h[w2][g2][t];
  g_part[blockIdx.x * BINS + t] = s;          // blockIdx = pg*SPLIT+split
}

// ---------------------------------------------------------------------------
// Reductions
// ---------------------------------------------------------------------------
__device__ __forceinline__ float wave_allsum(float v) {
  #pragma unroll
  for (int off = 32; off > 0; off >>= 1) v += __shfl_xor(v, off, 64);
  return v;
}
__device__ __forceinline__ float block_sum(float v, float* red, int lane, int wv) {
  v = wave_allsum(v);
  __syncthreads();
  if (lane == 0) red[wv] = v;
  __syncthreads();
  return red[0] + red[1] + red[2] + red[3];
}

// ---------------------------------------------------------------------------
// Kernel 2: per-pair KL + fused final mean (R13/R16 pattern, proven).
// ---------------------------------------------------------------------------
__global__ __launch_bounds__(256) void klfused_kernel(
    const float* __restrict__ g_part, unsigned int* __restrict__ fl1,
    unsigned int* __restrict__ fl2, float* __restrict__ out) {
  const int t = threadIdx.x, lane = t & 63, wv = t >> 6;
  const int p = blockIdx.x;

  if (p < NPAIR) {
    __shared__ float red[4];
    float ht = 0.f, hq = 0.f;
    #pragma unroll 8
    for (int s = 0; s < SPLIT; ++s) {
      ht += g_part[(p * SPLIT + s) * BINS + t];
      hq += g_part[((NPAIR + p) * SPLIT + s) * BINS + t];
    }
    ht *= INV_NORM;
    hq *= INV_NORM;

    const float st = block_sum(ht, red, lane, wv);
    const float sq = block_sum(hq, red, lane, wv);
    const float P = ht / (st + 1e-10f) + 1e-10f;
    const float Q = hq / (sq + 1e-10f) + 1e-10f;
    const float kl = block_sum(P * __logf(P / Q), red, lane, wv);
    if (t == 0) {
      const unsigned int b = __float_as_uint(kl);
      __hip_atomic_store(&fl1[p], b, __ATOMIC_RELEASE, __HIP_MEMORY_SCOPE_AGENT);
      __hip_atomic_store(&fl2[p], ~b, __ATOMIC_RELEASE, __HIP_MEMORY_SCOPE_AGENT);
    }
  } else {
    // finisher block: wave 0 only
    if (t >= 64) return;
    float v = 0.f;
    if (lane < NPAIR) {
      unsigned int a, b;
      do {
        a = __hip_atomic_load(&fl1[lane], __ATOMIC_ACQUIRE, __HIP_MEMORY_SCOPE_AGENT);
        b = __hip_atomic_load(&fl2[lane], __ATOMIC_ACQUIRE, __HIP_MEMORY_SCOPE_AGENT);
      } while (b != ~a);
      v = __uint_as_float(a);
    }
    v = wave_allsum(v);
    if (lane == 0) out[0] = v * (1.0f / NPAIR);
  }
}

// ---------------------------------------------------------------------------
extern "C" void kernel_launch(void* const* d_in, const int* in_sizes, int n_in,
                              void* d_out, int out_size, void* d_ws, size_t ws_size,
                              hipStream_t stream) {
  const float* targ = (const float*)d_in[0];
  const float* pred = (const float*)d_in[1];
  float* g_part = (float*)d_ws;                       // 1536*256 f32 = 1.5 MiB
  unsigned int* fl1 = (unsigned int*)(g_part + NBLK * BINS);  // 24 words
  unsigned int* fl2 = fl1 + NPAIR;                            // 24 words
  float* out = (float*)d_out;

  hist_kernel<<<dim3(NBLK), dim3(256), 0, stream>>>(targ, pred, g_part);
  klfused_kernel<<<dim3(NPAIR + 1), dim3(256), 0, stream>>>(g_part, fl1, fl2, out);
}

// Round 20
// 22.433 us; speedup vs baseline: 1.0369x; 1.0369x over previous
//
#include <hip/hip_runtime.h>
#include <math.h>

// Problem constants
#define BINS   256
#define NPAIR  24        // B*C = 8*3
#define NPIX   16384     // 128*128
#define SPLIT  16        // blocks per (tensor,channel); 32 tested worse (R11/R19)
#define NBLK   (48 * SPLIT)   // 768 blocks

#define DELTA    0.003921568859f           // 1/255 (bin pitch)
// exp2-folded constants
#define NK2      -7213.475204f             // -5000 * log2(e)
#define A2K2     56.57627611f              // (10000/255) * log2(e)
#define B2K2     0.11093398f               // 5000*DELTA^2 * log2(e)
#define RHO1     0.85745468f               // rho   = exp(-2*5000*DELTA^2)
#define RHO3     0.63042510f               // rho^3
#define RHO4     0.54056079f               // rho^4
#define INV_NORM 39.894228040143274f       // 1/(sigma*sqrt(2*pi))

typedef float v2f __attribute__((ext_vector_type(2)));

// In-place packed ops ("+v": read-modify-write, ZERO copies — R17's "=v"
// version forced a fresh dest pair + copy-back per op, which is why it
// regressed). Issue-bound kernel => wins come only from fewer instructions.
__device__ __forceinline__ void pkmul_ip(v2f& a, v2f b) {
  asm("v_pk_mul_f32 %0, %0, %1" : "+v"(a) : "v"(b));
}
__device__ __forceinline__ void pkadd_ip(v2f& a, v2f b) {
  asm("v_pk_add_f32 %0, %0, %1" : "+v"(a) : "v"(b));
}

// ---------------------------------------------------------------------------
// Kernel 1: soft histogram, register-gather, 16 bins/lane, paired recurrence,
// 2 pixels/round (R16 structure). R20 delta: the 4-bin/iter chain core is
// 6 in-place v_pk instructions exactly; both pixels accumulate straight into
// acc[i]. Inferred emitted-issue drops ~400 -> ~160 cyc/round.
// ---------------------------------------------------------------------------
__global__ __launch_bounds__(256) void hist_kernel(
    const float* __restrict__ targ, const float* __restrict__ pred,
    float* __restrict__ g_part) {
  __shared__ float h[4][4][BINS];   // [wave][subgroup][bin] = 16 KiB
  __shared__ float pxs[1024];       // block's pixel slab

  const int t = threadIdx.x, lane = t & 63, wv = t >> 6;
  const int g = lane >> 4, lsub = lane & 15;
  const int pg = blockIdx.x >> 4;            // 0..47
  const int split = blockIdx.x & (SPLIT - 1);
  const int chan = (pg < NPAIR) ? pg : pg - NPAIR;
  const float* __restrict__ src = (pg < NPAIR) ? targ : pred;

  // stage 1024 pixels: 256 threads x float4 (coalesced)
  reinterpret_cast<float4*>(pxs)[t] =
      reinterpret_cast<const float4*>(src + chan * NPIX + split * 1024)[t];
  __syncthreads();

  const float c0 = (float)(16 * lsub) * DELTA;  // lane's first bin center
  const v2f R44 = {RHO4, RHO4};

  v2f acc[8];
  #pragma unroll
  for (int i = 0; i < 8; ++i) acc[i] = (v2f){0.f, 0.f};

  #pragma unroll 2
  for (int r = 0; r < 32; ++r) {
    // subgroup g's two pixels this round (uniform per 16-lane subgroup)
    const float xA = pxs[wv * 256 + 8 * r + g];
    const float xB = pxs[wv * 256 + 8 * r + 4 + g];

    const float dA = xA - c0;
    const float dB = xB - c0;
    const float w0A = __builtin_amdgcn_exp2f(NK2 * dA * dA);
    const float w0B = __builtin_amdgcn_exp2f(NK2 * dB * dB);
    const float q0A = __builtin_amdgcn_exp2f(A2K2 * dA - B2K2);
    const float q0B = __builtin_amdgcn_exp2f(A2K2 * dB - B2K2);
    const float q2A = q0A * q0A;
    const float q2B = q0B * q0B;

    v2f wA; wA.x = w0A; wA.y = w0A * q0A;       // (w_0, w_1)
    v2f wB; wB.x = w0B; wB.y = w0B * q0B;
    v2f mA; mA.x = q2A * RHO1; mA.y = q2A * RHO3;
    v2f mB; mB.x = q2B * RHO1; mB.y = q2B * RHO3;

    pkadd_ip(acc[0], wA);
    pkadd_ip(acc[0], wB);
    #pragma unroll
    for (int i = 1; i < 8; ++i) {               // 6 pk-instr per iter, in-place
      pkmul_ip(wA, mA);
      pkmul_ip(wB, mB);
      pkmul_ip(mA, R44);
      pkmul_ip(mB, R44);
      pkadd_ip(acc[i], wA);
      pkadd_ip(acc[i], wB);
    }
  }

  // block combine: 16 (wave,subgroup) partials -> one 256-bin block partial
  #pragma unroll
  for (int i = 0; i < 8; i += 2)
    reinterpret_cast<float4*>(&h[wv][g][16 * lsub + 2 * i])[0] =
        make_float4(acc[i].x, acc[i].y, acc[i + 1].x, acc[i + 1].y);
  __syncthreads();

  float s = 0.f;
  #pragma unroll
  for (int w2 = 0; w2 < 4; ++w2)
    #pragma unroll
    for (int g2 = 0; g2 < 4; ++g2) s += h[w2][g2][t];
  g_part[blockIdx.x * BINS + t] = s;          // blockIdx = pg*SPLIT+split
}

// ---------------------------------------------------------------------------
// Reductions
// ---------------------------------------------------------------------------
__device__ __forceinline__ float wave_allsum(float v) {
  #pragma unroll
  for (int off = 32; off > 0; off >>= 1) v += __shfl_xor(v, off, 64);
  return v;
}
__device__ __forceinline__ float block_sum(float v, float* red, int lane, int wv) {
  v = wave_allsum(v);
  __syncthreads();
  if (lane == 0) red[wv] = v;
  __syncthreads();
  return red[0] + red[1] + red[2] + red[3];
}

// ---------------------------------------------------------------------------
// Kernel 2: per-pair KL + fused final mean (R13/R16 pattern, proven).
// ---------------------------------------------------------------------------
__global__ __launch_bounds__(256) void klfused_kernel(
    const float* __restrict__ g_part, unsigned int* __restrict__ fl1,
    unsigned int* __restrict__ fl2, float* __restrict__ out) {
  const int t = threadIdx.x, lane = t & 63, wv = t >> 6;
  const int p = blockIdx.x;

  if (p < NPAIR) {
    __shared__ float red[4];
    float ht = 0.f, hq = 0.f;
    #pragma unroll
    for (int s = 0; s < SPLIT; ++s) {
      ht += g_part[(p * SPLIT + s) * BINS + t];
      hq += g_part[((NPAIR + p) * SPLIT + s) * BINS + t];
    }
    ht *= INV_NORM;
    hq *= INV_NORM;

    const float st = block_sum(ht, red, lane, wv);
    const float sq = block_sum(hq, red, lane, wv);
    const float P = ht / (st + 1e-10f) + 1e-10f;
    const float Q = hq / (sq + 1e-10f) + 1e-10f;
    const float kl = block_sum(P * __logf(P / Q), red, lane, wv);
    if (t == 0) {
      const unsigned int b = __float_as_uint(kl);
      __hip_atomic_store(&fl1[p], b, __ATOMIC_RELEASE, __HIP_MEMORY_SCOPE_AGENT);
      __hip_atomic_store(&fl2[p], ~b, __ATOMIC_RELEASE, __HIP_MEMORY_SCOPE_AGENT);
    }
  } else {
    // finisher block: wave 0 only
    if (t >= 64) return;
    float v = 0.f;
    if (lane < NPAIR) {
      unsigned int a, b;
      do {
        a = __hip_atomic_load(&fl1[lane], __ATOMIC_ACQUIRE, __HIP_MEMORY_SCOPE_AGENT);
        b = __hip_atomic_load(&fl2[lane], __ATOMIC_ACQUIRE, __HIP_MEMORY_SCOPE_AGENT);
      } while (b != ~a);
      v = __uint_as_float(a);
    }
    v = wave_allsum(v);
    if (lane == 0) out[0] = v * (1.0f / NPAIR);
  }
}

// ---------------------------------------------------------------------------
extern "C" void kernel_launch(void* const* d_in, const int* in_sizes, int n_in,
                              void* d_out, int out_size, void* d_ws, size_t ws_size,
                              hipStream_t stream) {
  const float* targ = (const float*)d_in[0];
  const float* pred = (const float*)d_in[1];
  float* g_part = (float*)d_ws;                       // 768*256 f32 = 768 KiB
  unsigned int* fl1 = (unsigned int*)(g_part + NBLK * BINS);  // 24 words
  unsigned int* fl2 = fl1 + NPAIR;                            // 24 words
  float* out = (float*)d_out;

  hist_kernel<<<dim3(NBLK), dim3(256), 0, stream>>>(targ, pred, g_part);
  klfused_kernel<<<dim3(NPAIR + 1), dim3(256), 0, stream>>>(g_part, fl1, fl2, out);
}